// Round 1
// baseline (488.148 us; speedup 1.0000x reference)
//
#include <hip/hip_runtime.h>
#include <cstdint>
#include <cstddef>

#define Nn 2048
#define FIN 256
#define EFEAT 32
#define HID 64
#define NH 4
#define NL 3
#define LRELU_A 0.2f
#define NEGBIG -9.0e15f

__device__ __forceinline__ float rl_f(float v, int l) {
  return __builtin_bit_cast(float, __builtin_amdgcn_readlane(__builtin_bit_cast(int, v), l));
}

// ---------------- coef[l,h,f] = sum_i W_e[l,h,f,i] * (sum_o W[l,h,i,o]*a3[l,h,o]) ----------------
__global__ void k_coef(const float* __restrict__ W, const float* __restrict__ We,
                       const float* __restrict__ a, float* __restrict__ coef) {
  int lh = blockIdx.x;          // 0..11  (l*4+h)
  int t = threadIdx.x;          // 256
  __shared__ float tl[FIN];
  const float* Wb = W + (size_t)lh * FIN * HID;
  const float* ab = a + (size_t)lh * (3 * HID) + 2 * HID;
  float acc = 0.f;
#pragma unroll 8
  for (int o = 0; o < HID; ++o) acc = fmaf(Wb[(size_t)t * HID + o], ab[o], acc);
  tl[t] = acc;
  __syncthreads();
  if (t < EFEAT) {
    const float* Web = We + ((size_t)lh * EFEAT + t) * FIN;
    float c = 0.f;
    for (int i = 0; i < FIN; ++i) c = fmaf(Web[i], tl[i], c);
    coef[lh * EFEAT + t] = c;
  }
}

// ---------------- e-score precompute: es[c][nrel][m] = dot(e[n,m,:], coef[c,:]) or NEGBIG if masked
template <int C>
__global__ __launch_bounds__(256) void k_escore(
    const float* __restrict__ e, const int* __restrict__ adj,
    const float* __restrict__ coef, float* __restrict__ es,
    size_t ch_stride, int n0) {
  size_t idx = (size_t)blockIdx.x * 256 + threadIdx.x;   // nrel*Nn + m
  int m = (int)(idx & (Nn - 1));
  int nrel = (int)(idx >> 11);
  size_t gnm = ((size_t)(n0 + nrel) << 11) + (size_t)m;
  int aj = adj[gnm];
  if (aj == 0) {
#pragma unroll
    for (int c = 0; c < C; ++c) es[(size_t)c * ch_stride + idx] = NEGBIG;
    return;
  }
  const float4* ep = (const float4*)(e + gnm * EFEAT);
  float evv[EFEAT];
#pragma unroll
  for (int g = 0; g < 8; ++g) {
    float4 v = ep[g];
    evv[g * 4 + 0] = v.x; evv[g * 4 + 1] = v.y; evv[g * 4 + 2] = v.z; evv[g * 4 + 3] = v.w;
  }
  // keep c a real loop: per-iteration the 32 coef loads are wave-uniform -> s_loads,
  // acc is a scalar (no runtime-indexed register array)
#pragma clang loop unroll(disable)
  for (int c = 0; c < C; ++c) {
    const float* cf = coef + c * EFEAT;
    float acc = 0.f;
#pragma unroll
    for (int f = 0; f < EFEAT; ++f) acc = fmaf(evv[f], cf[f], acc);
    es[(size_t)c * ch_stride + idx] = acc;
  }
}

// ---------------- h = x @ W[l]  (+ s1 = h.a1, s2 = h.a2 wave-reductions) ----------------
__global__ __launch_bounds__(256) void k_h(
    const float* __restrict__ x, const float* __restrict__ W,
    const float* __restrict__ a, int layer,
    float* __restrict__ hbuf, float* __restrict__ s1, float* __restrict__ s2) {
  __shared__ __align__(16) float xs[8][FIN];
  int t = threadIdx.x;
  int n0 = blockIdx.x * 8;
#pragma unroll
  for (int j = 0; j < 8; ++j) xs[j][t] = x[(size_t)(n0 + j) * FIN + t];
  __syncthreads();
  int h = t >> 6, o = t & 63;
  const float* Wb = W + (((size_t)layer * NH + h) * FIN) * HID + o;
  float acc[8] = {};
  for (int i0 = 0; i0 < FIN; i0 += 4) {
    float w0 = Wb[(size_t)(i0 + 0) * HID];
    float w1 = Wb[(size_t)(i0 + 1) * HID];
    float w2 = Wb[(size_t)(i0 + 2) * HID];
    float w3 = Wb[(size_t)(i0 + 3) * HID];
#pragma unroll
    for (int j = 0; j < 8; ++j) {
      float4 xv = *(const float4*)&xs[j][i0];
      acc[j] = fmaf(xv.x, w0, acc[j]);
      acc[j] = fmaf(xv.y, w1, acc[j]);
      acc[j] = fmaf(xv.z, w2, acc[j]);
      acc[j] = fmaf(xv.w, w3, acc[j]);
    }
  }
  const float* ab = a + ((size_t)layer * NH + h) * (3 * HID);
  float a1v = ab[o], a2v = ab[HID + o];
#pragma unroll
  for (int j = 0; j < 8; ++j) {
    float r1 = acc[j] * a1v, r2 = acc[j] * a2v;
#pragma unroll
    for (int d = 1; d < 64; d <<= 1) {
      r1 += __shfl_xor(r1, d, 64);
      r2 += __shfl_xor(r2, d, 64);
    }
    if (o == 0) { s1[h * Nn + n0 + j] = r1; s2[h * Nn + n0 + j] = r2; }
    hbuf[((size_t)h * Nn + n0 + j) * HID + o] = acc[j];
  }
}

// ---------------- attention + h' = att @ h ----------------
// block = 4 waves; wave w handles 4 rows of head blockIdx.x; full-row softmax in registers;
// phase2 broadcasts p via v_readlane (VALU, per-SIMD) instead of LDS (per-CU).
__global__ __launch_bounds__(256, 2) void k_attn(
    const float* __restrict__ es, size_t ch_stride,
    const float* __restrict__ s1, const float* __restrict__ s2,
    const float* __restrict__ hbuf, float* __restrict__ hp, int n0) {
  int h = blockIdx.x;
  int t = threadIdx.x;
  int w = __builtin_amdgcn_readfirstlane(t >> 6);
  int lane = t & 63;
  int nrel = blockIdx.y * 16 + w * 4;
  const float* esb = es + (size_t)h * ch_stride + (size_t)nrel * Nn;
  const float* s2h = s2 + h * Nn;
  float p[4][32];
  float inv[4];
#pragma unroll
  for (int r = 0; r < 4; ++r) {
    float s1v = s1[h * Nn + n0 + nrel + r];
    const float* esr = esb + (size_t)r * Nn;
    float pm = -3.0e38f;
#pragma unroll
    for (int g = 0; g < 8; ++g) {
      float4 ev = *(const float4*)(esr + g * 256 + lane * 4);
      float4 sv = *(const float4*)(s2h + g * 256 + lane * 4);
      float c0 = s1v + sv.x + ev.x; c0 = c0 > 0.f ? c0 : LRELU_A * c0;
      float c1 = s1v + sv.y + ev.y; c1 = c1 > 0.f ? c1 : LRELU_A * c1;
      float c2 = s1v + sv.z + ev.z; c2 = c2 > 0.f ? c2 : LRELU_A * c2;
      float c3 = s1v + sv.w + ev.w; c3 = c3 > 0.f ? c3 : LRELU_A * c3;
      p[r][g * 4 + 0] = c0; p[r][g * 4 + 1] = c1;
      p[r][g * 4 + 2] = c2; p[r][g * 4 + 3] = c3;
      pm = fmaxf(pm, fmaxf(fmaxf(c0, c1), fmaxf(c2, c3)));
    }
#pragma unroll
    for (int d = 1; d < 64; d <<= 1) pm = fmaxf(pm, __shfl_xor(pm, d, 64));
    float ps = 0.f;
#pragma unroll
    for (int k = 0; k < 32; ++k) {
      float pe = __expf(p[r][k] - pm);
      p[r][k] = pe;
      ps += pe;
    }
#pragma unroll
    for (int d = 1; d < 64; d <<= 1) ps += __shfl_xor(ps, d, 64);
    inv[r] = 1.0f / ps;
  }
  // phase 2: lane = o; 4 rows share every h[m][o] load
  const float* hb = hbuf + (size_t)h * Nn * HID + lane;
  float acc[4] = {};
#pragma unroll
  for (int g = 0; g < 8; ++g) {
    const float* hg = hb + (size_t)g * 256 * HID;
#pragma unroll 4
    for (int i = 0; i < 64; ++i) {
      float hv0 = hg[(size_t)(i * 4 + 0) * HID];
      float hv1 = hg[(size_t)(i * 4 + 1) * HID];
      float hv2 = hg[(size_t)(i * 4 + 2) * HID];
      float hv3 = hg[(size_t)(i * 4 + 3) * HID];
#pragma unroll
      for (int r = 0; r < 4; ++r) {
        acc[r] = fmaf(rl_f(p[r][g * 4 + 0], i), hv0, acc[r]);
        acc[r] = fmaf(rl_f(p[r][g * 4 + 1], i), hv1, acc[r]);
        acc[r] = fmaf(rl_f(p[r][g * 4 + 2], i), hv2, acc[r]);
        acc[r] = fmaf(rl_f(p[r][g * 4 + 3], i), hv3, acc[r]);
      }
    }
  }
  float* hpb = hp + ((size_t)h * Nn + n0 + nrel) * HID + lane;
#pragma unroll
  for (int r = 0; r < 4; ++r) hpb[(size_t)r * HID] = acc[r] * inv[r];
}

// ---------------- layer epilogues ----------------
__global__ void k_xnext(const float* __restrict__ hp, float* __restrict__ xn) {
  int idx = blockIdx.x * 256 + threadIdx.x;   // N*256
  int n = idx >> 8, rem = idx & 255;
  int h = rem >> 6, o = rem & 63;
  float v = hp[((size_t)h * Nn + n) * HID + o];
  xn[idx] = v > 0.f ? v : expm1f(v);
}

__global__ void k_out(const float* __restrict__ hp, float* __restrict__ out) {
  int idx = blockIdx.x * 256 + threadIdx.x;   // N*64
  int n = idx >> 6, o = idx & 63;
  size_t b = (size_t)n * HID + o;
  float v = 0.25f * (hp[b] + hp[(size_t)Nn * HID + b] +
                     hp[2 * (size_t)Nn * HID + b] + hp[3 * (size_t)Nn * HID + b]);
  out[idx] = v > 0.f ? v : expm1f(v);
}

extern "C" void kernel_launch(void* const* d_in, const int* in_sizes, int n_in,
                              void* d_out, int out_size, void* d_ws, size_t ws_size,
                              hipStream_t stream) {
  const float* x_in = (const float*)d_in[0];
  const int* adj = (const int*)d_in[1];
  const float* e = (const float*)d_in[2];
  const float* We = (const float*)d_in[3];
  const float* W = (const float*)d_in[4];
  const float* a = (const float*)d_in[5];
  float* out = (float*)d_out;

  char* ws = (char*)d_ws;
  size_t off = 0;
  auto alloc = [&](size_t bytes) -> void* {
    off = (off + 255) & ~(size_t)255;
    void* p = ws + off;
    off += bytes;
    return p;
  };
  float* coef = (float*)alloc((size_t)NL * NH * EFEAT * sizeof(float));
  float* s1 = (float*)alloc((size_t)NH * Nn * sizeof(float));
  float* s2 = (float*)alloc((size_t)NH * Nn * sizeof(float));
  float* hbuf = (float*)alloc((size_t)NH * Nn * HID * sizeof(float));
  float* hp = (float*)alloc((size_t)NH * Nn * HID * sizeof(float));
  float* xA = (float*)alloc((size_t)Nn * FIN * sizeof(float));
  float* xB = (float*)alloc((size_t)Nn * FIN * sizeof(float));
  off = (off + 255) & ~(size_t)255;
  size_t remain = ws_size > off ? ws_size - off : 0;
  size_t bigNeed = (size_t)NL * NH * Nn * Nn * sizeof(float);  // 192 MiB
  bool big = remain >= bigNeed;
  float* es = (float*)(ws + off);
  int CH = Nn;
  if (!big) {
    size_t perRow = (size_t)NH * Nn * sizeof(float);  // 32 KB per chunk-row
    size_t ch = perRow ? remain / perRow : 0;
    if (ch > (size_t)Nn) ch = Nn;
    ch &= ~(size_t)15;
    if (ch < 16) ch = 16;  // below this ws is unusably small; proceed anyway
    CH = (int)ch;
  }

  hipLaunchKernelGGL(k_coef, dim3(NL * NH), dim3(256), 0, stream, W, We, a, coef);

  if (big) {
    size_t total = (size_t)Nn * Nn;
    hipLaunchKernelGGL((k_escore<NL * NH>), dim3((unsigned)(total / 256)), dim3(256), 0, stream,
                       e, adj, coef, es, total, 0);
  }

  for (int l = 0; l < NL; ++l) {
    const float* xcur = (l == 0) ? x_in : ((l == 1) ? xA : xB);
    hipLaunchKernelGGL(k_h, dim3(Nn / 8), dim3(256), 0, stream, xcur, W, a, l, hbuf, s1, s2);
    if (big) {
      size_t chs = (size_t)Nn * Nn;
      const float* esl = es + (size_t)l * NH * chs;
      hipLaunchKernelGGL(k_attn, dim3(NH, Nn / 16), dim3(256), 0, stream,
                         esl, chs, s1, s2, hbuf, hp, 0);
    } else {
      for (int c0 = 0; c0 < Nn; c0 += CH) {
        int rows = (Nn - c0 < CH) ? (Nn - c0) : CH;
        size_t chs = (size_t)rows * Nn;
        hipLaunchKernelGGL((k_escore<NH>), dim3((unsigned)(chs / 256)), dim3(256), 0, stream,
                           e, adj, coef + l * NH * EFEAT, es, chs, c0);
        hipLaunchKernelGGL(k_attn, dim3(NH, rows / 16), dim3(256), 0, stream,
                           es, chs, s1, s2, hbuf, hp, c0);
      }
    }
    if (l == NL - 1) {
      hipLaunchKernelGGL(k_out, dim3(Nn * HID / 256), dim3(256), 0, stream, hp, out);
    } else {
      float* xn = (l == 0) ? xA : xB;
      hipLaunchKernelGGL(k_xnext, dim3(Nn * FIN / 256), dim3(256), 0, stream, hp, xn);
    }
  }
}

// Round 3
// 279.207 us; speedup vs baseline: 1.7483x; 1.7483x over previous
//
#include <hip/hip_runtime.h>
#include <cstdint>
#include <cstddef>

#define Nn 2048
#define FIN 256
#define EFEAT 32
#define HID 64
#define NH 4
#define NL 3
#define LRELU_A 0.2f

typedef _Float16 h4 __attribute__((ext_vector_type(4)));
typedef _Float16 h8 __attribute__((ext_vector_type(8)));
typedef float f4 __attribute__((ext_vector_type(4)));

#define NEGH ((_Float16)(-60000.0f))

// ---------------- coef[l,h,f] = sum_i W_e[l,h,f,i] * (sum_o W[l,h,i,o]*a3[l,h,o]) ----------------
__global__ void k_coef(const float* __restrict__ W, const float* __restrict__ We,
                       const float* __restrict__ a, float* __restrict__ coef) {
  int lh = blockIdx.x;          // 0..11  (l*4+h)
  int t = threadIdx.x;          // 256
  __shared__ float tl[FIN];
  const float* Wb = W + (size_t)lh * FIN * HID;
  const float* ab = a + (size_t)lh * (3 * HID) + 2 * HID;
  float acc = 0.f;
#pragma unroll 8
  for (int o = 0; o < HID; ++o) acc = fmaf(Wb[(size_t)t * HID + o], ab[o], acc);
  tl[t] = acc;
  __syncthreads();
  if (t < EFEAT) {
    const float* Web = We + ((size_t)lh * EFEAT + t) * FIN;
    float c = 0.f;
    for (int i = 0; i < FIN; ++i) c = fmaf(Web[i], tl[i], c);
    coef[lh * EFEAT + t] = c;
  }
}

// ---------------- e-score precompute, fp16, m-tiled layout es[c][m/32][n][m%32] ----------------
template <int C>
__global__ __launch_bounds__(256) void k_escore(
    const float* __restrict__ e, const int* __restrict__ adj,
    const float* __restrict__ coef, _Float16* __restrict__ es) {
  size_t idx = (size_t)blockIdx.x * 256 + threadIdx.x;   // n*Nn + m
  int m = (int)(idx & (Nn - 1));
  int n = (int)(idx >> 11);
  int mt = m >> 5, ml = m & 31;
  const size_t cstride = (size_t)64 * Nn * 32;
  size_t sbase = ((size_t)mt * Nn + n) * 32 + (size_t)ml;
  int aj = adj[idx];
  if (aj == 0) {
#pragma unroll
    for (int c = 0; c < C; ++c) es[(size_t)c * cstride + sbase] = NEGH;
    return;
  }
  const float4* ep = (const float4*)(e + idx * EFEAT);
  float evv[EFEAT];
#pragma unroll
  for (int g = 0; g < 8; ++g) {
    float4 v = ep[g];
    evv[g * 4 + 0] = v.x; evv[g * 4 + 1] = v.y; evv[g * 4 + 2] = v.z; evv[g * 4 + 3] = v.w;
  }
#pragma clang loop unroll(disable)
  for (int c = 0; c < C; ++c) {
    const float* cf = coef + c * EFEAT;   // wave-uniform -> s_load
    float acc = 0.f;
#pragma unroll
    for (int f = 0; f < EFEAT; ++f) acc = fmaf(evv[f], cf[f], acc);
    es[(size_t)c * cstride + sbase] = (_Float16)acc;
  }
}

// ---------------- h = x @ W[l]; emit hT fp16 m-tiled [h][n/32][o][n%32], s1, s2 ----------------
// x loads are wave-uniform (scalarize to s_load); W loads lane-coalesced; no LDS.
__global__ __launch_bounds__(256) void k_h(
    const float* __restrict__ x, const float* __restrict__ W,
    const float* __restrict__ a, int layer,
    _Float16* __restrict__ hT, float* __restrict__ s1, float* __restrict__ s2) {
  int t = threadIdx.x;
  int n0 = blockIdx.x * 8;
  int h = t >> 6, o = t & 63;
  const float* Wb = W + ((size_t)(layer * NH + h) * FIN) * HID + o;
  const float* xb = x + (size_t)n0 * FIN;
  float acc[8] = {};
  for (int i0 = 0; i0 < FIN; i0 += 4) {
    float w0 = Wb[(size_t)(i0 + 0) * HID];
    float w1 = Wb[(size_t)(i0 + 1) * HID];
    float w2 = Wb[(size_t)(i0 + 2) * HID];
    float w3 = Wb[(size_t)(i0 + 3) * HID];
#pragma unroll
    for (int j = 0; j < 8; ++j) {
      float4 xv = *(const float4*)(xb + (size_t)j * FIN + i0);   // uniform -> SGPR
      acc[j] = fmaf(xv.x, w0, acc[j]);
      acc[j] = fmaf(xv.y, w1, acc[j]);
      acc[j] = fmaf(xv.z, w2, acc[j]);
      acc[j] = fmaf(xv.w, w3, acc[j]);
    }
  }
  const float* ab = a + (size_t)(layer * NH + h) * (3 * HID);
  float a1v = ab[o], a2v = ab[HID + o];
#pragma unroll
  for (int j = 0; j < 8; ++j) {
    float r1 = acc[j] * a1v, r2 = acc[j] * a2v;
#pragma unroll
    for (int d = 1; d < 64; d <<= 1) {
      r1 += __shfl_xor(r1, d, 64);
      r2 += __shfl_xor(r2, d, 64);
    }
    if (o == 0) { s1[h * Nn + n0 + j] = r1; s2[h * Nn + n0 + j] = r2; }
  }
  int mt = n0 >> 5, ml = n0 & 31;
  h8 hv;
#pragma unroll
  for (int j = 0; j < 8; ++j) hv[j] = (_Float16)acc[j];
  *(h8*)(hT + (((size_t)h * 64 + mt) * 64 + o) * 32 + ml) = hv;
}

// ---------------- attention: h'^T = h^T @ p^T via mfma_f32_16x16x16f16, online softmax ----------------
// block = 4 waves, one head, 16 rows (n0..n0+15). Wave w covers m in [w*512, w*512+512).
// Lane l: row n = n0 + (l&15); m-subchunk = (l>>4)*4 + j  (B-fragment layout, no transposes).
// A = hT tile (o x m), B = p tile (m x n), D = h'^T: row=(l>>4)*4+reg -> o, col=l&15 -> n.
__global__ __launch_bounds__(256) void k_attn(
    const _Float16* __restrict__ es, const _Float16* __restrict__ hT,
    const float* __restrict__ s1, const float* __restrict__ s2,
    float* __restrict__ hp, int layer) {
  int h = blockIdx.x;
  int n0 = blockIdx.y * 16;
  int t = threadIdx.x;
  int w = t >> 6;
  int l = t & 63;
  int col = l & 15, grp = l >> 4;
  int n = n0 + col;
  float s1v = s1[h * Nn + n];
  const _Float16* esb = es + (size_t)(layer * NH + h) * ((size_t)64 * Nn * 32);
  const _Float16* hTb = hT + (size_t)h * ((size_t)64 * 64 * 32);
  const float* s2b = s2 + h * Nn;

  float M = -3.0e38f, S = 0.f;
  f4 acc[4] = {};

  for (int c16 = 0; c16 < 32; ++c16) {
    int m0 = w * 512 + c16 * 16;
    int mt = m0 >> 5;
    int ml0 = (m0 & 31) + grp * 4;
    // scores (B-fragment layout)
    h4 ev = *(const h4*)(esb + ((size_t)mt * Nn + n) * 32 + ml0);
    float4 sv = *(const float4*)(s2b + m0 + grp * 4);
    float sc0 = s1v + sv.x + (float)ev[0]; sc0 = fmaxf(sc0, LRELU_A * sc0);
    float sc1 = s1v + sv.y + (float)ev[1]; sc1 = fmaxf(sc1, LRELU_A * sc1);
    float sc2 = s1v + sv.z + (float)ev[2]; sc2 = fmaxf(sc2, LRELU_A * sc2);
    float sc3 = s1v + sv.w + (float)ev[3]; sc3 = fmaxf(sc3, LRELU_A * sc3);
    float cm = fmaxf(fmaxf(sc0, sc1), fmaxf(sc2, sc3));
    cm = fmaxf(cm, __shfl_xor(cm, 16, 64));   // combine 4 groups (same row set)
    cm = fmaxf(cm, __shfl_xor(cm, 32, 64));
    float Mn = fmaxf(M, cm);
    float fac = __expf(M - Mn);               // first chunk: exp(-huge)=0, acc/S are 0 anyway
    M = Mn;
    S *= fac;
#pragma unroll
    for (int ot = 0; ot < 4; ++ot) acc[ot] *= fac;
    h4 pb;
    pb[0] = (_Float16)__expf(sc0 - Mn);
    pb[1] = (_Float16)__expf(sc1 - Mn);
    pb[2] = (_Float16)__expf(sc2 - Mn);
    pb[3] = (_Float16)__expf(sc3 - Mn);
    S += (float)pb[0] + (float)pb[1] + (float)pb[2] + (float)pb[3];
    const _Float16* hp0 = hTb + ((size_t)mt * 64 + col) * 32 + ml0;
#pragma unroll
    for (int ot = 0; ot < 4; ++ot) {
      h4 af = *(const h4*)(hp0 + (size_t)ot * 16 * 32);
      acc[ot] = __builtin_amdgcn_mfma_f32_16x16x16f16(af, pb, acc[ot], 0, 0, 0);
    }
  }

  // reduce S across the 4 groups (same row)
  S += __shfl_xor(S, 16, 64);
  S += __shfl_xor(S, 32, 64);

  __shared__ float red[4][16][64];
  __shared__ float Mw[4][16];
  __shared__ float Sw[4][16];
  if (l < 16) { Mw[w][l] = M; Sw[w][l] = S; }
#pragma unroll
  for (int ot = 0; ot < 4; ++ot)
    *(f4*)&red[w][col][ot * 16 + grp * 4] = acc[ot];
  __syncthreads();

  // combine 4 waves (different m-ranges, different running max)
  int nl = t >> 4, o0 = (t & 15) * 4;
  float Ms = fmaxf(fmaxf(Mw[0][nl], Mw[1][nl]), fmaxf(Mw[2][nl], Mw[3][nl]));
  float Ssum = 0.f;
  f4 v = {};
#pragma unroll
  for (int ww = 0; ww < 4; ++ww) {
    float f = __expf(Mw[ww][nl] - Ms);
    Ssum = fmaf(Sw[ww][nl], f, Ssum);
    f4 r = *(const f4*)&red[ww][nl][o0];
    v += r * f;
  }
  float is = 1.0f / Ssum;
  *(f4*)(hp + ((size_t)h * Nn + n0 + nl) * HID + o0) = v * is;
}

// ---------------- layer epilogues ----------------
__global__ void k_xnext(const float* __restrict__ hp, float* __restrict__ xn) {
  int idx = blockIdx.x * 256 + threadIdx.x;   // N*256
  int n = idx >> 8, rem = idx & 255;
  int h = rem >> 6, o = rem & 63;
  float v = hp[((size_t)h * Nn + n) * HID + o];
  xn[idx] = v > 0.f ? v : expm1f(v);
}

__global__ void k_out(const float* __restrict__ hp, float* __restrict__ out) {
  int idx = blockIdx.x * 256 + threadIdx.x;   // N*64
  int n = idx >> 6, o = idx & 63;
  size_t b = (size_t)n * HID + o;
  float v = 0.25f * (hp[b] + hp[(size_t)Nn * HID + b] +
                     hp[2 * (size_t)Nn * HID + b] + hp[3 * (size_t)Nn * HID + b]);
  out[idx] = v > 0.f ? v : expm1f(v);
}

extern "C" void kernel_launch(void* const* d_in, const int* in_sizes, int n_in,
                              void* d_out, int out_size, void* d_ws, size_t ws_size,
                              hipStream_t stream) {
  const float* x_in = (const float*)d_in[0];
  const int* adj = (const int*)d_in[1];
  const float* e = (const float*)d_in[2];
  const float* We = (const float*)d_in[3];
  const float* W = (const float*)d_in[4];
  const float* a = (const float*)d_in[5];
  float* out = (float*)d_out;

  char* ws = (char*)d_ws;
  size_t off = 0;
  auto alloc = [&](size_t bytes) -> void* {
    off = (off + 255) & ~(size_t)255;
    void* p = ws + off;
    off += bytes;
    return p;
  };
  float* coef = (float*)alloc((size_t)NL * NH * EFEAT * sizeof(float));
  float* s1 = (float*)alloc((size_t)NH * Nn * sizeof(float));
  float* s2 = (float*)alloc((size_t)NH * Nn * sizeof(float));
  float* hp = (float*)alloc((size_t)NH * Nn * HID * sizeof(float));
  float* xA = (float*)alloc((size_t)Nn * FIN * sizeof(float));
  float* xB = (float*)alloc((size_t)Nn * FIN * sizeof(float));
  _Float16* hT = (_Float16*)alloc((size_t)NH * 64 * 64 * 32 * sizeof(_Float16));
  _Float16* es = (_Float16*)alloc((size_t)NL * NH * 64 * Nn * 32 * sizeof(_Float16));

  hipLaunchKernelGGL(k_coef, dim3(NL * NH), dim3(256), 0, stream, W, We, a, coef);

  size_t total = (size_t)Nn * Nn;
  hipLaunchKernelGGL((k_escore<NL * NH>), dim3((unsigned)(total / 256)), dim3(256), 0, stream,
                     e, adj, coef, es);

  for (int l = 0; l < NL; ++l) {
    const float* xcur = (l == 0) ? x_in : ((l == 1) ? xA : xB);
    hipLaunchKernelGGL(k_h, dim3(Nn / 8), dim3(256), 0, stream, xcur, W, a, l, hT, s1, s2);
    hipLaunchKernelGGL(k_attn, dim3(NH, Nn / 16), dim3(256), 0, stream,
                       es, hT, s1, s2, hp, l);
    if (l == NL - 1) {
      hipLaunchKernelGGL(k_out, dim3(Nn * HID / 256), dim3(256), 0, stream, hp, out);
    } else {
      float* xn = (l == 0) ? xA : xB;
      hipLaunchKernelGGL(k_xnext, dim3(Nn * FIN / 256), dim3(256), 0, stream, hp, xn);
    }
  }
}